// Round 1
// baseline (727.904 us; speedup 1.0000x reference)
//
#include <hip/hip_runtime.h>
#include <math.h>

// Problem constants
#define HI 1024
#define WI 1024
#define HO 512
#define WO 512
#define CIN 64
#define COUT 128
#define NW (3*3*CIN*COUT)   // 73728 fused 3x3 weights
#define NGROUP 32

// ws layout (bytes):
//   xd     : 0            .. 67108864   (512*512*64 f32)
//   Wf     : 67108864     .. 67403776   (3*3*64*128 f32)
//   bf     : 67403776     .. 67404288   (128 f32 + pad)
//   part   : 67404288     .. 67928576   (2048 blocks * 64 f32 partial sums)
//   params : 67928576     .. 67928832   (mu[32], inv_std[32])
// total ~68 MB (requires ws_size >= 67928832)

__device__ __forceinline__ float gelu_tanh(float x) {
    // jax.nn.gelu approximate=True
    float x3 = x * x * x;
    float a = 0.7978845608028654f * (x + 0.044715f * x3);
    return 0.5f * x * (1.0f + tanhf(a));
}

// K0: fold 1x1 conv into 3x3 center tap, fold biases
__global__ void k_fold(const float* __restrict__ W1, const float* __restrict__ b1,
                       const float* __restrict__ W2, const float* __restrict__ b2,
                       float* __restrict__ Wf, float* __restrict__ bf) {
    int idx = blockIdx.x * 256 + threadIdx.x;
    if (idx < NW) {
        float v = W1[idx];
        int tap = idx >> 13;              // / (64*128)
        if (tap == 4) v += W2[idx - (4 << 13)];  // center tap (dy=1,dx=1)
        Wf[idx] = v;
    } else if (idx < NW + COUT) {
        int c = idx - NW;
        bf[c] = b1[c] + b2[c];
    }
}

// K1: bilinear downsample with the reference's TRANSPOSED sampling:
//   xd[i][j][c] = bilinear(x, row = lin[j], col = lin[i]), lin = linspace(0,1024,512)
//   out-of-range taps (coordinate 1024) zero-fill, matching map_coordinates order=1.
__global__ void k_down(const float* __restrict__ x, float* __restrict__ xd) {
    int t = blockIdx.x * 256 + threadIdx.x;
    if (t >= HO * WO * (CIN / 4)) return;
    int c4 = t & 15;               // 16 float4 chunks of 64 channels
    int j  = (t >> 4) & (WO - 1);
    int i  = t >> 13;
    const float step = 1024.0f / 511.0f;
    float tr = (float)j * step;    // row coordinate depends on j (transpose!)
    float tc = (float)i * step;    // col coordinate depends on i
    int r0 = (int)tr; float fr = tr - (float)r0;
    int c0 = (int)tc; float fc = tc - (float)c0;
    float w00 = (1.f - fr) * (1.f - fc);
    float w01 = (1.f - fr) * fc;
    float w10 = fr * (1.f - fc);
    float w11 = fr * fc;
    float4 acc = make_float4(0.f, 0.f, 0.f, 0.f);
    int cc = c4 << 2;
    #define TAP(R, C, W) \
        if ((R) < HI && (C) < WI) { \
            const float4 v = *(const float4*)&x[(((R) << 10) + (C)) * CIN + cc]; \
            acc.x += (W) * v.x; acc.y += (W) * v.y; acc.z += (W) * v.z; acc.w += (W) * v.w; \
        }
    TAP(r0,     c0,     w00)
    TAP(r0,     c0 + 1, w01)
    TAP(r0 + 1, c0,     w10)
    TAP(r0 + 1, c0 + 1, w11)
    #undef TAP
    *(float4*)&xd[(((i << 9) + j) * CIN) + cc] = acc;
}

// K2: fused 3x3 conv (with folded 1x1) -> y (written to d_out)
// Block: 256 threads = 16 co-blocks(8 co) x 16 px-groups(4 px). Tile 8x8 px.
__global__ __launch_bounds__(256) void k_conv(const float* __restrict__ xd,
        const float* __restrict__ Wf, const float* __restrict__ bf,
        float* __restrict__ y) {
    __shared__ float lx[CIN][100];   // [ci][(row)*10 + col], 10x10 halo tile
    int tid = threadIdx.x;
    int tr0 = (blockIdx.x >> 6) << 3;
    int tc0 = (blockIdx.x & 63) << 3;
    // stage tile (with halo, zero-padded at image edges), transposing to [ci][px]
    for (int l = tid; l < 1600; l += 256) {
        int c4 = l & 15;
        int p  = l >> 4;            // 0..99
        int pr = p / 10, pc = p - pr * 10;
        int gr = tr0 + pr - 1, gc = tc0 + pc - 1;
        float4 v = make_float4(0.f, 0.f, 0.f, 0.f);
        if (gr >= 0 && gr < HO && gc >= 0 && gc < WO)
            v = *(const float4*)&xd[((gr << 9) + gc) * CIN + (c4 << 2)];
        int ci = c4 << 2;
        lx[ci][p] = v.x; lx[ci + 1][p] = v.y; lx[ci + 2][p] = v.z; lx[ci + 3][p] = v.w;
    }
    __syncthreads();

    int cb = tid & 15, pg = tid >> 4;
    int lr = pg >> 1, lc0 = (pg & 1) << 2;
    int co0 = cb << 3;
    float acc[4][8];
    float4 bfa = *(const float4*)&bf[co0];
    float4 bfb = *(const float4*)&bf[co0 + 4];
    #pragma unroll
    for (int p = 0; p < 4; ++p) {
        acc[p][0] = bfa.x; acc[p][1] = bfa.y; acc[p][2] = bfa.z; acc[p][3] = bfa.w;
        acc[p][4] = bfb.x; acc[p][5] = bfb.y; acc[p][6] = bfb.z; acc[p][7] = bfb.w;
    }
    #pragma unroll
    for (int dy = 0; dy < 3; ++dy) {
        #pragma unroll
        for (int dx = 0; dx < 3; ++dx) {
            const float* wp = Wf + ((dy * 3 + dx) * CIN) * COUT + co0;
            const float* xr = &lx[0][(lr + dy) * 10 + lc0 + dx];
            #pragma unroll 4
            for (int ci = 0; ci < CIN; ++ci) {
                float4 wa = *(const float4*)(wp + ci * COUT);
                float4 wb = *(const float4*)(wp + ci * COUT + 4);
                float xv[4];
                xv[0] = xr[ci * 100 + 0];
                xv[1] = xr[ci * 100 + 1];
                xv[2] = xr[ci * 100 + 2];
                xv[3] = xr[ci * 100 + 3];
                #pragma unroll
                for (int p = 0; p < 4; ++p) {
                    acc[p][0] += xv[p] * wa.x;
                    acc[p][1] += xv[p] * wa.y;
                    acc[p][2] += xv[p] * wa.z;
                    acc[p][3] += xv[p] * wa.w;
                    acc[p][4] += xv[p] * wb.x;
                    acc[p][5] += xv[p] * wb.y;
                    acc[p][6] += xv[p] * wb.z;
                    acc[p][7] += xv[p] * wb.w;
                }
            }
        }
    }
    int orow = tr0 + lr;
    #pragma unroll
    for (int p = 0; p < 4; ++p) {
        float* op = y + ((orow << 9) + tc0 + lc0 + p) * COUT + co0;
        *(float4*)op       = make_float4(acc[p][0], acc[p][1], acc[p][2], acc[p][3]);
        *(float4*)(op + 4) = make_float4(acc[p][4], acc[p][5], acc[p][6], acc[p][7]);
    }
}

// K3: per-block partial group sums (deterministic, no float atomics)
// Block = (row, quarter): 2048 blocks; each covers 128 px x 128 ch.
__global__ void k_stats(const float* __restrict__ y, float* __restrict__ part) {
    __shared__ float ls[256], ls2[256];
    int row = blockIdx.x >> 2;
    int q   = blockIdx.x & 3;
    int tid = threadIdx.x;
    int c   = tid & 127;
    int ph  = tid >> 7;
    const float* p = y + (size_t)row * (WO * COUT);
    float s = 0.f, s2 = 0.f;
    for (int px = q * 128 + ph; px < (q + 1) * 128; px += 2) {
        float v = p[px * COUT + c];
        s += v; s2 += v * v;
    }
    ls[tid] = s; ls2[tid] = s2;
    __syncthreads();
    if (tid < 32) {
        float gs = 0.f, gs2 = 0.f;
        #pragma unroll
        for (int k = 0; k < 4; ++k) {
            int c0 = tid * 4 + k;
            gs  += ls[c0] + ls[128 + c0];
            gs2 += ls2[c0] + ls2[128 + c0];
        }
        part[blockIdx.x * 64 + tid]      = gs;
        part[blockIdx.x * 64 + 32 + tid] = gs2;
    }
}

// K4: reduce 2048 partials -> mu[g], inv_std[g]
__global__ void k_final(const float* __restrict__ part, float* __restrict__ params) {
    int t = threadIdx.x;  // 64 threads: t<32 sums, t>=32 sumsqs
    float s = 0.f;
    for (int r = 0; r < 2048; ++r) s += part[r * 64 + t];
    __shared__ float sh[64];
    sh[t] = s;
    __syncthreads();
    if (t < 32) {
        const float invN = 1.0f / (512.0f * 512.0f * 4.0f);
        float mu  = sh[t] * invN;
        float var = sh[32 + t] * invN - mu * mu;
        params[t]      = mu;
        params[32 + t] = rsqrtf(var + 1e-5f);
    }
}

// K5: normalize + scale/bias + tanh-GELU, in place on d_out
__global__ void k_gelu(float* __restrict__ y, const float* __restrict__ params,
                       const float* __restrict__ scale, const float* __restrict__ bias,
                       int n4) {
    int t = blockIdx.x * 256 + threadIdx.x;
    if (t >= n4) return;
    int g  = t & 31;        // 4 consecutive channels = one group (float4-aligned)
    int c0 = g << 2;
    float4 v = ((float4*)y)[t];
    float mu = params[g], inv = params[32 + g];
    float4 sc = *(const float4*)&scale[c0];
    float4 bi = *(const float4*)&bias[c0];
    v.x = gelu_tanh((v.x - mu) * inv * sc.x + bi.x);
    v.y = gelu_tanh((v.y - mu) * inv * sc.y + bi.y);
    v.z = gelu_tanh((v.z - mu) * inv * sc.z + bi.z);
    v.w = gelu_tanh((v.w - mu) * inv * sc.w + bi.w);
    ((float4*)y)[t] = v;
}

extern "C" void kernel_launch(void* const* d_in, const int* in_sizes, int n_in,
                              void* d_out, int out_size, void* d_ws, size_t ws_size,
                              hipStream_t stream) {
    const float* x  = (const float*)d_in[0];
    const float* W1 = (const float*)d_in[1];
    const float* b1 = (const float*)d_in[2];
    const float* W2 = (const float*)d_in[3];
    const float* b2 = (const float*)d_in[4];
    const float* gs = (const float*)d_in[5];
    const float* gb = (const float*)d_in[6];
    float* out = (float*)d_out;

    char* ws = (char*)d_ws;
    float* xd     = (float*)(ws);
    float* Wf     = (float*)(ws + 67108864);
    float* bf     = (float*)(ws + 67403776);
    float* part   = (float*)(ws + 67404288);
    float* params = (float*)(ws + 67928576);

    k_fold<<<(NW + COUT + 255) / 256, 256, 0, stream>>>(W1, b1, W2, b2, Wf, bf);
    k_down<<<(HO * WO * (CIN / 4)) / 256, 256, 0, stream>>>(x, xd);
    k_conv<<<4096, 256, 0, stream>>>(xd, Wf, bf, out);
    k_stats<<<2048, 256, 0, stream>>>(out, part);
    k_final<<<1, 64, 0, stream>>>(part, params);
    k_gelu<<<(out_size / 4 + 255) / 256, 256, 0, stream>>>(out, params, gs, gb, out_size / 4);
}

// Round 2
// 229.247 us; speedup vs baseline: 3.1752x; 3.1752x over previous
//
#include <hip/hip_runtime.h>
#include <math.h>

// Problem constants
#define HI 1024
#define WI 1024
#define HO 512
#define WO 512
#define CIN 64
#define COUT 128
#define NW (9*CIN*COUT)   // 73728 fused 3x3 weights

typedef __attribute__((ext_vector_type(8))) short bf16x8;
typedef __attribute__((ext_vector_type(4))) float f32x4;

// ws layout (bytes):
//   xd     : 0         .. 33554432   (512*512*64 bf16)
//   Bpk    : 33554432  .. 33701888   (9*2*8*64*8 bf16, MFMA-fragment order)
//   bf     : 33701888  .. 33702400   (128 f32 fused bias)
//   part   : 33702400  .. 33964544   (1024 blocks * 64 f32 partials)
//   params : 33964544  .. 33964800   (mu[32], inv_std[32])

__device__ __forceinline__ unsigned short f2bf(float f) {   // round-to-nearest-even
    unsigned u = __float_as_uint(f);
    u += 0x7fffu + ((u >> 16) & 1u);
    return (unsigned short)(u >> 16);
}

__device__ __forceinline__ float gelu_tanh(float x) {
    float x3 = x * x * x;
    float a = 0.7978845608028654f * (x + 0.044715f * x3);
    return 0.5f * x * (1.0f + tanhf(a));
}

// K0: fold 1x1 into 3x3 center tap; pack weights into MFMA B-fragment lane order (bf16).
// Bpk[t][h][nf][lane][j]: B[k = h*32 + (lane>>4)*8 + j][cout = nf*16 + (lane&15)] for tap t.
__global__ void k_pack(const float* __restrict__ W1, const float* __restrict__ b1,
                       const float* __restrict__ W2, const float* __restrict__ b2,
                       unsigned short* __restrict__ Bpk, float* __restrict__ bf) {
    int idx = blockIdx.x * 256 + threadIdx.x;
    if (idx < NW) {
        int j  = idx & 7;
        int l  = (idx >> 3) & 63;
        int nf = (idx >> 9) & 7;
        int h  = (idx >> 12) & 1;
        int t  = idx >> 13;
        int cin  = (h << 5) + ((l >> 4) << 3) + j;
        int cout = (nf << 4) + (l & 15);
        float v = W1[(t * 64 + cin) * 128 + cout];
        if (t == 4) v += W2[cin * 128 + cout];   // center tap gets the 1x1 conv
        Bpk[idx] = f2bf(v);
    } else if (idx < NW + COUT) {
        int c = idx - NW;
        bf[c] = b1[c] + b2[c];
    }
}

// K1: bilinear downsample (reference's transposed sampling), output bf16.
__global__ void k_down(const float* __restrict__ x, unsigned short* __restrict__ xd) {
    int t = blockIdx.x * 256 + threadIdx.x;
    if (t >= HO * WO * (CIN / 4)) return;
    int c4 = t & 15;
    int j  = (t >> 4) & (WO - 1);
    int i  = t >> 13;
    const float step = 1024.0f / 511.0f;
    float tr = (float)j * step;    // row coordinate depends on j (transpose!)
    float tc = (float)i * step;    // col coordinate depends on i
    int r0 = (int)tr; float fr = tr - (float)r0;
    int c0 = (int)tc; float fc = tc - (float)c0;
    float w00 = (1.f - fr) * (1.f - fc);
    float w01 = (1.f - fr) * fc;
    float w10 = fr * (1.f - fc);
    float w11 = fr * fc;
    float4 acc = make_float4(0.f, 0.f, 0.f, 0.f);
    int cc = c4 << 2;
    #define TAP(R, C, W) \
        if ((R) < HI && (C) < WI) { \
            const float4 v = *(const float4*)&x[(((R) << 10) + (C)) * CIN + cc]; \
            acc.x += (W) * v.x; acc.y += (W) * v.y; acc.z += (W) * v.z; acc.w += (W) * v.w; \
        }
    TAP(r0,     c0,     w00)
    TAP(r0,     c0 + 1, w01)
    TAP(r0 + 1, c0,     w10)
    TAP(r0 + 1, c0 + 1, w11)
    #undef TAP
    ushort4 o;
    o.x = f2bf(acc.x); o.y = f2bf(acc.y); o.z = f2bf(acc.z); o.w = f2bf(acc.w);
    *(ushort4*)&xd[(((i << 9) + j) * CIN) + cc] = o;
}

// K2: MFMA conv. Block = 16x16 px x 128 cout, 4 waves (each: 8x8 px quadrant x 128 cout).
// Fuses GroupNorm partial-sum reduction into the epilogue.
__global__ __launch_bounds__(256, 2) void k_conv(
        const unsigned short* __restrict__ xd,
        const unsigned short* __restrict__ Bpk,
        const float* __restrict__ bf,
        float* __restrict__ y, float* __restrict__ part) {
    __shared__ short lxs[324 * 64];        // 18x18 halo tile x 64cin bf16, col-swizzled (41472 B)
    __shared__ short lbs[2 * 8 * 64 * 8];  // one tap's B fragments (16384 B)
    __shared__ float sred[4][64];

    const int tid = threadIdx.x;
    const int l   = tid & 63;
    const int w   = tid >> 6;
    const int gr0 = (blockIdx.x >> 5) << 4;
    const int gc0 = (blockIdx.x & 31) << 4;

    // stage halo tile: pos = row*18+col, 8 chunks of 16B per pos; chunk XOR-swizzled by col
    for (int idx = tid; idx < 324 * 8; idx += 256) {
        int pos = idx >> 3, c = idx & 7;
        int row = pos / 18;
        int col = pos - row * 18;
        int gr = gr0 + row - 1, gc = gc0 + col - 1;
        uint4 v = make_uint4(0u, 0u, 0u, 0u);
        if (gr >= 0 && gr < HO && gc >= 0 && gc < WO)
            v = *(const uint4*)&xd[((gr << 9) + gc) * 64 + (c << 3)];
        *(uint4*)((char*)lxs + pos * 128 + ((c ^ (col & 7)) << 4)) = v;
    }

    const int wr0 = (w >> 1) << 3;   // wave quadrant origin in the 16x16 tile
    const int wc0 = (w & 1) << 3;
    const int qg  = l >> 4;
    const int colbase = wc0 + (l & 7);
    int rowbase[4];
    #pragma unroll
    for (int mf = 0; mf < 4; ++mf)
        rowbase[mf] = (wr0 + 2 * mf + ((l & 15) >> 3)) * 18 + colbase;

    f32x4 acc[4][8];
    #pragma unroll
    for (int nf = 0; nf < 8; ++nf) {
        float b = bf[(nf << 4) + (l & 15)];
        #pragma unroll
        for (int mf = 0; mf < 4; ++mf)
            acc[mf][nf] = (f32x4){b, b, b, b};
    }

    for (int t = 0; t < 9; ++t) {
        __syncthreads();   // protect lbs from previous tap's readers (also covers halo staging at t=0)
        {
            const uint4* src = (const uint4*)(Bpk + t * 8192);
            uint4* dst = (uint4*)lbs;
            #pragma unroll
            for (int i = 0; i < 4; ++i) {
                int idx = tid + i * 256;
                dst[idx] = src[idx];
            }
        }
        __syncthreads();

        const int dy = (t * 11) >> 5;   // t/3
        const int dx = t - dy * 3;
        #pragma unroll
        for (int h = 0; h < 2; ++h) {
            bf16x8 a[4], b[8];
            #pragma unroll
            for (int mf = 0; mf < 4; ++mf) {
                int pos = rowbase[mf] + dy * 18 + dx;
                int chunkx = ((h << 2) + qg) ^ ((colbase + dx) & 7);
                a[mf] = *(const bf16x8*)((const char*)lxs + pos * 128 + (chunkx << 4));
            }
            #pragma unroll
            for (int nf = 0; nf < 8; ++nf)
                b[nf] = *(const bf16x8*)((const char*)lbs + ((((h << 3) + nf) << 6) + l) * 16);
            #pragma unroll
            for (int mf = 0; mf < 4; ++mf) {
                #pragma unroll
                for (int nf = 0; nf < 8; ++nf)
                    acc[mf][nf] = __builtin_amdgcn_mfma_f32_16x16x32_bf16(
                        a[mf], b[nf], acc[mf][nf], 0, 0, 0);
            }
        }
    }

    // epilogue: store y (f32) + per-group partial sums for GroupNorm
    float s[8], s2[8];
    #pragma unroll
    for (int nf = 0; nf < 8; ++nf) { s[nf] = 0.f; s2[nf] = 0.f; }
    #pragma unroll
    for (int mf = 0; mf < 4; ++mf) {
        #pragma unroll
        for (int r = 0; r < 4; ++r) {
            int m  = (qg << 2) + r;                      // D row = (lane>>4)*4 + reg (m89)
            int gr = gr0 + wr0 + (mf << 1) + (m >> 3);
            int gc = gc0 + wc0 + (m & 7);
            float* op = y + (((gr << 9) + gc) << 7) + (l & 15);
            #pragma unroll
            for (int nf = 0; nf < 8; ++nf) {
                float v = acc[mf][nf][r];
                op[nf << 4] = v;
                s[nf]  += v;
                s2[nf] += v * v;
            }
        }
    }
    // group g = nf*4 + ((l&15)>>2); reduce over lane bits {0,1,4,5}
    #pragma unroll
    for (int nf = 0; nf < 8; ++nf) {
        s[nf]  += __shfl_xor(s[nf], 1);   s[nf]  += __shfl_xor(s[nf], 2);
        s[nf]  += __shfl_xor(s[nf], 16);  s[nf]  += __shfl_xor(s[nf], 32);
        s2[nf] += __shfl_xor(s2[nf], 1);  s2[nf] += __shfl_xor(s2[nf], 2);
        s2[nf] += __shfl_xor(s2[nf], 16); s2[nf] += __shfl_xor(s2[nf], 32);
    }
    if ((l & 0x33) == 0) {
        int gsub = l >> 2;   // l in {0,4,8,12} -> 0..3
        #pragma unroll
        for (int nf = 0; nf < 8; ++nf) {
            sred[w][(nf << 2) + gsub]      = s[nf];
            sred[w][32 + (nf << 2) + gsub] = s2[nf];
        }
    }
    __syncthreads();
    if (tid < 64)
        part[(blockIdx.x << 6) + tid] =
            sred[0][tid] + sred[1][tid] + sred[2][tid] + sred[3][tid];
}

// K3: reduce 1024 block partials -> mu[g], inv_std[g]
__global__ void k_final(const float* __restrict__ part, float* __restrict__ params) {
    __shared__ float sh[256];
    int t = threadIdx.x;
    int col = t & 63, q = t >> 6;
    float s = 0.f;
    for (int r = q; r < 1024; r += 4) s += part[r * 64 + col];
    sh[t] = s;
    __syncthreads();
    if (t < 64) sh[t] = sh[t] + sh[64 + t] + sh[128 + t] + sh[192 + t];
    __syncthreads();
    if (t < 32) {
        const float invN = 1.0f / (512.0f * 512.0f * 4.0f);
        float mu  = sh[t] * invN;
        float var = sh[32 + t] * invN - mu * mu;
        params[t]      = mu;
        params[32 + t] = rsqrtf(var + 1e-5f);
    }
}

// K4: normalize + scale/bias + tanh-GELU, in place on d_out
__global__ void k_gelu(float* __restrict__ y, const float* __restrict__ params,
                       const float* __restrict__ scale, const float* __restrict__ bias,
                       int n4) {
    int t = blockIdx.x * 256 + threadIdx.x;
    if (t >= n4) return;
    int g  = t & 31;
    int c0 = g << 2;
    float4 v = ((float4*)y)[t];
    float mu = params[g], inv = params[32 + g];
    float4 sc = *(const float4*)&scale[c0];
    float4 bi = *(const float4*)&bias[c0];
    v.x = gelu_tanh((v.x - mu) * inv * sc.x + bi.x);
    v.y = gelu_tanh((v.y - mu) * inv * sc.y + bi.y);
    v.z = gelu_tanh((v.z - mu) * inv * sc.z + bi.z);
    v.w = gelu_tanh((v.w - mu) * inv * sc.w + bi.w);
    ((float4*)y)[t] = v;
}

extern "C" void kernel_launch(void* const* d_in, const int* in_sizes, int n_in,
                              void* d_out, int out_size, void* d_ws, size_t ws_size,
                              hipStream_t stream) {
    const float* x  = (const float*)d_in[0];
    const float* W1 = (const float*)d_in[1];
    const float* b1 = (const float*)d_in[2];
    const float* W2 = (const float*)d_in[3];
    const float* b2 = (const float*)d_in[4];
    const float* gs = (const float*)d_in[5];
    const float* gb = (const float*)d_in[6];
    float* out = (float*)d_out;

    char* ws = (char*)d_ws;
    unsigned short* xd  = (unsigned short*)(ws);
    unsigned short* Bpk = (unsigned short*)(ws + 33554432);
    float* bf           = (float*)(ws + 33701888);
    float* part         = (float*)(ws + 33702400);
    float* params       = (float*)(ws + 33964544);

    k_pack<<<(NW + COUT + 255) / 256, 256, 0, stream>>>(W1, b1, W2, b2, Bpk, bf);
    k_down<<<(HO * WO * (CIN / 4)) / 256, 256, 0, stream>>>(x, xd);
    k_conv<<<1024, 256, 0, stream>>>(xd, Bpk, bf, out, part);
    k_final<<<1, 256, 0, stream>>>(part, params);
    k_gelu<<<(out_size / 4) / 256, 256, 0, stream>>>(out, params, gs, gb, out_size / 4);
}